// Round 2
// baseline (365.511 us; speedup 1.0000x reference)
//
#include <hip/hip_runtime.h>

typedef __attribute__((ext_vector_type(8))) short s16x8;
typedef __attribute__((ext_vector_type(4))) float f32x4;

#define SCALE 0.125f
#define LOG2E 1.4426950408889634f

__device__ inline float b2f(unsigned short u) {
    union { unsigned int i; float f; } x; x.i = ((unsigned int)u) << 16; return x.f;
}
__device__ inline unsigned short f2b(float f) {
    union { float f; unsigned int i; } x; x.f = f;
    unsigned int i = x.i;
    unsigned int r = (i + 0x7FFFu + ((i >> 16) & 1u)) >> 16;
    return (unsigned short)r;
}

// ---------------- f32 -> bf16 convert (x) ----------------
__global__ __launch_bounds__(256) void cvt_f32_bf16(
    const float* __restrict__ in, unsigned short* __restrict__ out) {
    int i = (blockIdx.x * 256 + threadIdx.x) * 8;
    f32x4 a = *(const f32x4*)(in + i);
    f32x4 b = *(const f32x4*)(in + i + 4);
    s16x8 o;
    o[0] = (short)f2b(a[0]); o[1] = (short)f2b(a[1]);
    o[2] = (short)f2b(a[2]); o[3] = (short)f2b(a[3]);
    o[4] = (short)f2b(b[0]); o[5] = (short)f2b(b[1]);
    o[6] = (short)f2b(b[2]); o[7] = (short)f2b(b[3]);
    *(s16x8*)(out + i) = o;
}

// ---------------- transpose f32 -> bf16: in[R][C] -> out[C][R] ----------------
__global__ __launch_bounds__(256) void transpose_f32_bf16(
    const float* __restrict__ in, unsigned short* __restrict__ out,
    int R, int C) {
    __shared__ unsigned short tile[64][72];
    int tc = blockIdx.x * 64, tr = blockIdx.y * 64;
    int t = threadIdx.x;
    int r = t >> 2, cq = (t & 3) * 16;
    const float* src = in + (size_t)(tr + r) * C + tc + cq;
#pragma unroll
    for (int j = 0; j < 16; j += 4) {
        f32x4 v = *(const f32x4*)(src + j);
        tile[r][cq + j]     = f2b(v[0]);
        tile[r][cq + j + 1] = f2b(v[1]);
        tile[r][cq + j + 2] = f2b(v[2]);
        tile[r][cq + j + 3] = f2b(v[3]);
    }
    __syncthreads();
    int oc = t >> 2, rq = (t & 3) * 16;
    s16x8 w0, w1;
#pragma unroll
    for (int j = 0; j < 8; j++) {
        w0[j] = (short)tile[rq + j][oc];
        w1[j] = (short)tile[rq + 8 + j][oc];
    }
    s16x8* dst = (s16x8*)(out + (size_t)(tc + oc) * R + tr + rq);
    dst[0] = w0; dst[1] = w1;
}

// ---------------- RoPE tables from rotation matrix (f32) ----------------
// R[l, 2i, 2i] = cos, R[l, 2i+1, 2i] = sin
__global__ __launch_bounds__(256) void rope_tables(
    const float* __restrict__ R, float* __restrict__ cosT,
    float* __restrict__ sinT) {
    int idx = blockIdx.x * 256 + threadIdx.x;  // L*32
    int l = idx >> 5, i = idx & 31;
    size_t base = (size_t)l * 4096;
    cosT[idx] = R[base + (size_t)(2 * i) * 64 + 2 * i];
    sinT[idx] = R[base + (size_t)(2 * i + 1) * 64 + 2 * i];
}

// ---------------- GEMM: A[M][K] bf16, BT[N][K] bf16 -> C[M][N] ----------
template <bool F32OUT>
__global__ __launch_bounds__(256) void gemm_bf16(
    const unsigned short* __restrict__ A, const unsigned short* __restrict__ BT,
    void* __restrict__ Cv, int M, int N, int K) {
    __shared__ unsigned short As[128][40];
    __shared__ unsigned short Bs[128][40];
    int t = threadIdx.x;
    int wave = t >> 6, lane = t & 63, lo = lane & 15, hi = lane >> 4;
    int m0 = blockIdx.y * 128, n0 = blockIdx.x * 128;
    int wr = wave >> 1, wc = wave & 1;
    int sr = t >> 1, sh = (t & 1) * 16;

    f32x4 acc[4][4] = {};

    for (int k0 = 0; k0 < K; k0 += 32) {
        const s16x8* ga = (const s16x8*)(A + (size_t)(m0 + sr) * K + k0 + sh);
        s16x8 a0 = ga[0], a1 = ga[1];
        const s16x8* gb = (const s16x8*)(BT + (size_t)(n0 + sr) * K + k0 + sh);
        s16x8 b0 = gb[0], b1 = gb[1];
        *(s16x8*)&As[sr][sh] = a0; *(s16x8*)&As[sr][sh + 8] = a1;
        *(s16x8*)&Bs[sr][sh] = b0; *(s16x8*)&Bs[sr][sh + 8] = b1;
        __syncthreads();
        s16x8 af[4], bfr[4];
#pragma unroll
        for (int i = 0; i < 4; i++)
            af[i] = *(const s16x8*)&As[wr * 64 + i * 16 + lo][hi * 8];
#pragma unroll
        for (int j = 0; j < 4; j++)
            bfr[j] = *(const s16x8*)&Bs[wc * 64 + j * 16 + lo][hi * 8];
#pragma unroll
        for (int i = 0; i < 4; i++)
#pragma unroll
            for (int j = 0; j < 4; j++)
                acc[i][j] = __builtin_amdgcn_mfma_f32_16x16x32_bf16(
                    af[i], bfr[j], acc[i][j], 0, 0, 0);
        __syncthreads();
    }
#pragma unroll
    for (int i = 0; i < 4; i++)
#pragma unroll
        for (int j = 0; j < 4; j++)
#pragma unroll
            for (int r = 0; r < 4; r++) {
                int row = m0 + wr * 64 + i * 16 + hi * 4 + r;
                int col = n0 + wc * 64 + j * 16 + lo;
                if (F32OUT)
                    ((float*)Cv)[(size_t)row * N + col] = acc[i][j][r];
                else
                    ((unsigned short*)Cv)[(size_t)row * N + col] = f2b(acc[i][j][r]);
            }
}

// ---------------- RoPE in-place on Q [2048][2048] bf16 ----------------
__global__ __launch_bounds__(256) void rope_q(
    unsigned int* __restrict__ Q, const float* __restrict__ cosT,
    const float* __restrict__ sinT) {
    int idx = blockIdx.x * 256 + threadIdx.x;  // L * 1024 pairs
    int l = idx >> 10, p = idx & 1023, i = p & 31;
    unsigned int v = Q[(size_t)l * 1024 + p];
    float x = b2f((unsigned short)(v & 0xffff));
    float y = b2f((unsigned short)(v >> 16));
    float c = cosT[l * 32 + i], s = sinT[l * 32 + i];
    float xr = c * x - s * y, yr = s * x + c * y;
    Q[(size_t)l * 1024 + p] = (unsigned int)f2b(xr) | ((unsigned int)f2b(yr) << 16);
}

// ---- RoPE in-place on K [2048][512] bf16 + write repeated f32 out ----
__global__ __launch_bounds__(256) void rope_k_out(
    unsigned int* __restrict__ K, const float* __restrict__ cosT,
    const float* __restrict__ sinT, float* __restrict__ outK) {
    int idx = blockIdx.x * 256 + threadIdx.x;  // L * 256 pairs
    int l = idx >> 8, p = idx & 255, kvh = p >> 5, i = p & 31;
    unsigned int v = K[(size_t)l * 256 + p];
    float x = b2f((unsigned short)(v & 0xffff));
    float y = b2f((unsigned short)(v >> 16));
    float c = cosT[l * 32 + i], s = sinT[l * 32 + i];
    float xr = c * x - s * y, yr = s * x + c * y;
    K[(size_t)l * 256 + p] = (unsigned int)f2b(xr) | ((unsigned int)f2b(yr) << 16);
#pragma unroll
    for (int rep = 0; rep < 4; rep++) {
        int h = kvh * 4 + rep;
        size_t o = ((size_t)h * 2048 + l) * 64 + 2 * i;
        outK[o] = xr;
        outK[o + 1] = yr;
    }
}

// ---------------- V repeated f32 out ----------------
__global__ __launch_bounds__(256) void v_out(
    const unsigned short* __restrict__ V, float* __restrict__ outV) {
    int idx = blockIdx.x * 256 + threadIdx.x;  // L * 64 chunks of 8
    int l = idx >> 6, c8 = idx & 63;
    int kvh = c8 >> 3, d0 = (c8 & 7) * 8;
    s16x8 v = *(const s16x8*)(V + (size_t)l * 512 + c8 * 8);
    float f[8];
#pragma unroll
    for (int j = 0; j < 8; j++) f[j] = b2f((unsigned short)v[j]);
#pragma unroll
    for (int rep = 0; rep < 4; rep++) {
        int h = kvh * 4 + rep;
        float* dst = outV + ((size_t)h * 2048 + l) * 64 + d0;
        *(f32x4*)dst = *(f32x4*)&f[0];
        *(f32x4*)(dst + 4) = *(f32x4*)&f[4];
    }
}

// ---------------- flash attention (causal), bf16 in/out ----------------
__global__ __launch_bounds__(256) void attn(
    const unsigned short* __restrict__ Q, const unsigned short* __restrict__ Kr,
    const unsigned short* __restrict__ V, unsigned short* __restrict__ Oa) {
    __shared__ unsigned short Ks[64][72];
    __shared__ unsigned short Vt[64][72];
    __shared__ unsigned short Ps[4][16][72];
    int h = blockIdx.x, qb = blockIdx.y;
    int t = threadIdx.x, wave = t >> 6, lane = t & 63, lo = lane & 15, hi = lane >> 4;
    int kvh = h >> 2;

    int qrow = qb * 64 + wave * 16 + lo;
    s16x8 qf0 = *(const s16x8*)(Q + (size_t)qrow * 2048 + h * 64 + hi * 8);
    s16x8 qf1 = *(const s16x8*)(Q + (size_t)qrow * 2048 + h * 64 + 32 + hi * 8);

    f32x4 o[4] = {};
    float m[4], ll[4];
#pragma unroll
    for (int r = 0; r < 4; r++) { m[r] = -1e30f; ll[r] = 0.0f; }

    int srow = t >> 2, scol = (t & 3) * 16;
    const float sc = SCALE * LOG2E;

    for (int kb = 0; kb <= qb; kb++) {
        const s16x8* gk = (const s16x8*)(Kr + (size_t)(kb * 64 + srow) * 512 + kvh * 64 + scol);
        s16x8 k0 = gk[0], k1 = gk[1];
        *(s16x8*)&Ks[srow][scol] = k0;
        *(s16x8*)&Ks[srow][scol + 8] = k1;
        const s16x8* gv = (const s16x8*)(V + (size_t)(kb * 64 + srow) * 512 + kvh * 64 + scol);
        s16x8 v0 = gv[0], v1 = gv[1];
#pragma unroll
        for (int j = 0; j < 8; j++) {
            Vt[scol + j][srow] = (unsigned short)v0[j];
            Vt[scol + 8 + j][srow] = (unsigned short)v1[j];
        }
        __syncthreads();

        f32x4 s[4];
#pragma unroll
        for (int tt = 0; tt < 4; tt++) {
            s16x8 kb0 = *(const s16x8*)&Ks[tt * 16 + lo][hi * 8];
            s16x8 kb1 = *(const s16x8*)&Ks[tt * 16 + lo][32 + hi * 8];
            f32x4 z = {};
            z = __builtin_amdgcn_mfma_f32_16x16x32_bf16(qf0, kb0, z, 0, 0, 0);
            z = __builtin_amdgcn_mfma_f32_16x16x32_bf16(qf1, kb1, z, 0, 0, 0);
            s[tt] = z;
        }

        bool diag = (kb == qb);
#pragma unroll
        for (int r = 0; r < 4; r++) {
            int qloc = wave * 16 + hi * 4 + r;
            float mx = -1e30f;
#pragma unroll
            for (int tt = 0; tt < 4; tt++) {
                float val = s[tt][r] * sc;
                if (diag && (tt * 16 + lo) > qloc) val = -1e30f;
                s[tt][r] = val;
                mx = fmaxf(mx, val);
            }
            mx = fmaxf(mx, __shfl_xor(mx, 1));
            mx = fmaxf(mx, __shfl_xor(mx, 2));
            mx = fmaxf(mx, __shfl_xor(mx, 4));
            mx = fmaxf(mx, __shfl_xor(mx, 8));
            float mn = fmaxf(m[r], mx);
            float al = exp2f(m[r] - mn);
            float rs = 0.0f;
#pragma unroll
            for (int tt = 0; tt < 4; tt++) {
                float p = exp2f(s[tt][r] - mn);
                s[tt][r] = p;
                rs += p;
            }
            rs += __shfl_xor(rs, 1);
            rs += __shfl_xor(rs, 2);
            rs += __shfl_xor(rs, 4);
            rs += __shfl_xor(rs, 8);
            ll[r] = ll[r] * al + rs;
            m[r] = mn;
#pragma unroll
            for (int dt = 0; dt < 4; dt++) o[dt][r] *= al;
#pragma unroll
            for (int tt = 0; tt < 4; tt++)
                Ps[wave][hi * 4 + r][tt * 16 + lo] = f2b(s[tt][r]);
        }
        __syncthreads();

        s16x8 pa0 = *(const s16x8*)&Ps[wave][lo][hi * 8];
        s16x8 pa1 = *(const s16x8*)&Ps[wave][lo][32 + hi * 8];
#pragma unroll
        for (int dt = 0; dt < 4; dt++) {
            s16x8 vb0 = *(const s16x8*)&Vt[dt * 16 + lo][hi * 8];
            s16x8 vb1 = *(const s16x8*)&Vt[dt * 16 + lo][32 + hi * 8];
            o[dt] = __builtin_amdgcn_mfma_f32_16x16x32_bf16(pa0, vb0, o[dt], 0, 0, 0);
            o[dt] = __builtin_amdgcn_mfma_f32_16x16x32_bf16(pa1, vb1, o[dt], 0, 0, 0);
        }
        __syncthreads();
    }

    float inv[4];
#pragma unroll
    for (int r = 0; r < 4; r++) inv[r] = 1.0f / ll[r];
#pragma unroll
    for (int dt = 0; dt < 4; dt++)
#pragma unroll
        for (int r = 0; r < 4; r++) {
            int row = qb * 64 + wave * 16 + hi * 4 + r;
            Oa[(size_t)row * 2048 + h * 64 + dt * 16 + lo] = f2b(o[dt][r] * inv[r]);
        }
}

extern "C" void kernel_launch(void* const* d_in, const int* in_sizes, int n_in,
                              void* d_out, int out_size, void* d_ws, size_t ws_size,
                              hipStream_t stream) {
    const float* x  = (const float*)d_in[0];
    const float* R  = (const float*)d_in[1];
    // d_in[2] = mask: unused (causal mask applied analytically)
    const float* wq = (const float*)d_in[3];
    const float* wk = (const float*)d_in[4];
    const float* wv = (const float*)d_in[5];
    const float* wo = (const float*)d_in[6];

    float* out0 = (float*)d_out;
    float* outK = out0 + (size_t)2048 * 2048;
    float* outV = outK + (size_t)32 * 2048 * 64;

    char* ws = (char*)d_ws;
    unsigned short* wqT = (unsigned short*)(ws);                 // 8 MB
    unsigned short* wkT = (unsigned short*)(ws + 8388608);       // 2 MB
    unsigned short* wvT = (unsigned short*)(ws + 10485760);      // 2 MB
    unsigned short* woT = (unsigned short*)(ws + 12582912);      // 8 MB
    unsigned short* Qb  = (unsigned short*)(ws + 20971520);      // 8 MB
    unsigned short* Kb  = (unsigned short*)(ws + 29360128);      // 2 MB
    unsigned short* Vb  = (unsigned short*)(ws + 31457280);      // 2 MB
    unsigned short* Ob  = (unsigned short*)(ws + 33554432);      // 8 MB
    float* cosT = (float*)(ws + 41943040);                       // 256 KB
    float* sinT = (float*)(ws + 42205184);                       // 256 KB
    unsigned short* xb  = (unsigned short*)(ws + 42467328);      // 8 MB

    cvt_f32_bf16<<<2048, 256, 0, stream>>>(x, xb);
    transpose_f32_bf16<<<dim3(32, 32), 256, 0, stream>>>(wq, wqT, 2048, 2048);
    transpose_f32_bf16<<<dim3(8, 32), 256, 0, stream>>>(wk, wkT, 2048, 512);
    transpose_f32_bf16<<<dim3(8, 32), 256, 0, stream>>>(wv, wvT, 2048, 512);
    transpose_f32_bf16<<<dim3(32, 32), 256, 0, stream>>>(wo, woT, 2048, 2048);
    rope_tables<<<256, 256, 0, stream>>>(R, cosT, sinT);

    gemm_bf16<false><<<dim3(16, 16), 256, 0, stream>>>(xb, wqT, Qb, 2048, 2048, 2048);
    gemm_bf16<false><<<dim3(4, 16), 256, 0, stream>>>(xb, wkT, Kb, 2048, 512, 2048);
    gemm_bf16<false><<<dim3(4, 16), 256, 0, stream>>>(xb, wvT, Vb, 2048, 512, 2048);

    rope_q<<<8192, 256, 0, stream>>>((unsigned int*)Qb, cosT, sinT);
    rope_k_out<<<2048, 256, 0, stream>>>((unsigned int*)Kb, cosT, sinT, outK);
    v_out<<<512, 256, 0, stream>>>(Vb, outV);

    attn<<<dim3(32, 32), 256, 0, stream>>>(Qb, Kb, Vb, Ob);

    gemm_bf16<true><<<dim3(16, 16), 256, 0, stream>>>(Ob, woT, out0, 2048, 2048, 2048);
}

// Round 3
// 246.418 us; speedup vs baseline: 1.4833x; 1.4833x over previous
//
#include <hip/hip_runtime.h>

typedef __attribute__((ext_vector_type(8))) short s16x8;
typedef __attribute__((ext_vector_type(4))) float f32x4;

#define SCALE 0.125f
#define LOG2E 1.4426950408889634f
#define QSC (SCALE * LOG2E)

__device__ inline float b2f(unsigned short u) {
    union { unsigned int i; float f; } x; x.i = ((unsigned int)u) << 16; return x.f;
}
__device__ inline unsigned short f2b(float f) {
    union { float f; unsigned int i; } x; x.f = f;
    unsigned int i = x.i;
    unsigned int r = (i + 0x7FFFu + ((i >> 16) & 1u)) >> 16;
    return (unsigned short)r;
}

// ---------------- f32 -> bf16 convert (x) ----------------
__global__ __launch_bounds__(256) void cvt_f32_bf16(
    const float* __restrict__ in, unsigned short* __restrict__ out) {
    int i = (blockIdx.x * 256 + threadIdx.x) * 8;
    f32x4 a = *(const f32x4*)(in + i);
    f32x4 b = *(const f32x4*)(in + i + 4);
    s16x8 o;
    o[0] = (short)f2b(a[0]); o[1] = (short)f2b(a[1]);
    o[2] = (short)f2b(a[2]); o[3] = (short)f2b(a[3]);
    o[4] = (short)f2b(b[0]); o[5] = (short)f2b(b[1]);
    o[6] = (short)f2b(b[2]); o[7] = (short)f2b(b[3]);
    *(s16x8*)(out + i) = o;
}

// ------------- transpose f32 -> bf16: in[R][C] -> out[C][R] -------------
__global__ __launch_bounds__(256) void transpose_f32_bf16(
    const float* __restrict__ in, unsigned short* __restrict__ out,
    int R, int C) {
    __shared__ unsigned short tile[64][72];
    int tc = blockIdx.x * 64, tr = blockIdx.y * 64;
    int t = threadIdx.x;
    int r = t >> 2, cq = (t & 3) * 16;
    const float* src = in + (size_t)(tr + r) * C + tc + cq;
#pragma unroll
    for (int j = 0; j < 16; j += 4) {
        f32x4 v = *(const f32x4*)(src + j);
        tile[r][cq + j]     = f2b(v[0]);
        tile[r][cq + j + 1] = f2b(v[1]);
        tile[r][cq + j + 2] = f2b(v[2]);
        tile[r][cq + j + 3] = f2b(v[3]);
    }
    __syncthreads();
    int oc = t >> 2, rq = (t & 3) * 16;
    s16x8 w0, w1;
#pragma unroll
    for (int j = 0; j < 8; j++) {
        w0[j] = (short)tile[rq + j][oc];
        w1[j] = (short)tile[rq + 8 + j][oc];
    }
    s16x8* dst = (s16x8*)(out + (size_t)(tc + oc) * R + tr + rq);
    dst[0] = w0; dst[1] = w1;
}

// ------------- transpose bf16: in[R][C] -> out[C][R] (for V^T) -------------
__global__ __launch_bounds__(256) void transpose_bf16(
    const unsigned short* __restrict__ in, unsigned short* __restrict__ out,
    int R, int C) {
    __shared__ unsigned short tile[64][72];
    int tc = blockIdx.x * 64, tr = blockIdx.y * 64;
    int t = threadIdx.x;
    int r = t >> 2, cq = (t & 3) * 16;
    const s16x8* src = (const s16x8*)(in + (size_t)(tr + r) * C + tc + cq);
    s16x8 v0 = src[0], v1 = src[1];
    *(s16x8*)&tile[r][cq] = v0;
    *(s16x8*)&tile[r][cq + 8] = v1;
    __syncthreads();
    int oc = t >> 2, rq = (t & 3) * 16;
    s16x8 w0, w1;
#pragma unroll
    for (int j = 0; j < 8; j++) {
        w0[j] = (short)tile[rq + j][oc];
        w1[j] = (short)tile[rq + 8 + j][oc];
    }
    s16x8* dst = (s16x8*)(out + (size_t)(tc + oc) * R + tr + rq);
    dst[0] = w0; dst[1] = w1;
}

// ---------------- RoPE tables from rotation matrix (f32) ----------------
__global__ __launch_bounds__(256) void rope_tables(
    const float* __restrict__ R, float* __restrict__ cosT,
    float* __restrict__ sinT) {
    int idx = blockIdx.x * 256 + threadIdx.x;  // L*32
    int l = idx >> 5, i = idx & 31;
    size_t base = (size_t)l * 4096;
    cosT[idx] = R[base + (size_t)(2 * i) * 64 + 2 * i];
    sinT[idx] = R[base + (size_t)(2 * i + 1) * 64 + 2 * i];
}

// ---- fused QKV GEMM: A[2048][2048] bf16, BT[3072][2048] bf16 ----
__global__ __launch_bounds__(256) void gemm_qkv(
    const unsigned short* __restrict__ A, const unsigned short* __restrict__ BT,
    unsigned short* __restrict__ Qb, unsigned short* __restrict__ Kb,
    unsigned short* __restrict__ Vb) {
    const int K = 2048;
    __shared__ unsigned short As[128][40];
    __shared__ unsigned short Bs[128][40];
    int t = threadIdx.x;
    int wave = t >> 6, lane = t & 63, lo = lane & 15, hi = lane >> 4;
    int m0 = blockIdx.y * 128, n0 = blockIdx.x * 128;
    int wr = wave >> 1, wc = wave & 1;
    int sr = t >> 1, sh = (t & 1) * 16;

    f32x4 acc[4][4] = {};

    for (int k0 = 0; k0 < K; k0 += 32) {
        const s16x8* ga = (const s16x8*)(A + (size_t)(m0 + sr) * K + k0 + sh);
        s16x8 a0 = ga[0], a1 = ga[1];
        const s16x8* gb = (const s16x8*)(BT + (size_t)(n0 + sr) * K + k0 + sh);
        s16x8 b0 = gb[0], b1 = gb[1];
        *(s16x8*)&As[sr][sh] = a0; *(s16x8*)&As[sr][sh + 8] = a1;
        *(s16x8*)&Bs[sr][sh] = b0; *(s16x8*)&Bs[sr][sh + 8] = b1;
        __syncthreads();
        s16x8 af[4], bfr[4];
#pragma unroll
        for (int i = 0; i < 4; i++)
            af[i] = *(const s16x8*)&As[wr * 64 + i * 16 + lo][hi * 8];
#pragma unroll
        for (int j = 0; j < 4; j++)
            bfr[j] = *(const s16x8*)&Bs[wc * 64 + j * 16 + lo][hi * 8];
#pragma unroll
        for (int i = 0; i < 4; i++)
#pragma unroll
            for (int j = 0; j < 4; j++)
                acc[i][j] = __builtin_amdgcn_mfma_f32_16x16x32_bf16(
                    af[i], bfr[j], acc[i][j], 0, 0, 0);
        __syncthreads();
    }
    unsigned short* dst; int N, cb;
    if (n0 < 2048)      { dst = Qb; N = 2048; cb = n0; }
    else if (n0 < 2560) { dst = Kb; N = 512;  cb = n0 - 2048; }
    else                { dst = Vb; N = 512;  cb = n0 - 2560; }
#pragma unroll
    for (int i = 0; i < 4; i++)
#pragma unroll
        for (int j = 0; j < 4; j++)
#pragma unroll
            for (int r = 0; r < 4; r++) {
                int row = m0 + wr * 64 + i * 16 + hi * 4 + r;
                int col = cb + wc * 64 + j * 16 + lo;
                dst[(size_t)row * N + col] = f2b(acc[i][j][r]);
            }
}

// -------- GEMM: A[M][K] bf16, BT[N][K] bf16 -> C[M][N] f32 (output) --------
__global__ __launch_bounds__(256) void gemm_out(
    const unsigned short* __restrict__ A, const unsigned short* __restrict__ BT,
    float* __restrict__ C, int M, int N, int K) {
    __shared__ unsigned short As[128][40];
    __shared__ unsigned short Bs[128][40];
    int t = threadIdx.x;
    int wave = t >> 6, lane = t & 63, lo = lane & 15, hi = lane >> 4;
    int m0 = blockIdx.y * 128, n0 = blockIdx.x * 128;
    int wr = wave >> 1, wc = wave & 1;
    int sr = t >> 1, sh = (t & 1) * 16;

    f32x4 acc[4][4] = {};

    for (int k0 = 0; k0 < K; k0 += 32) {
        const s16x8* ga = (const s16x8*)(A + (size_t)(m0 + sr) * K + k0 + sh);
        s16x8 a0 = ga[0], a1 = ga[1];
        const s16x8* gb = (const s16x8*)(BT + (size_t)(n0 + sr) * K + k0 + sh);
        s16x8 b0 = gb[0], b1 = gb[1];
        *(s16x8*)&As[sr][sh] = a0; *(s16x8*)&As[sr][sh + 8] = a1;
        *(s16x8*)&Bs[sr][sh] = b0; *(s16x8*)&Bs[sr][sh + 8] = b1;
        __syncthreads();
        s16x8 af[4], bfr[4];
#pragma unroll
        for (int i = 0; i < 4; i++)
            af[i] = *(const s16x8*)&As[wr * 64 + i * 16 + lo][hi * 8];
#pragma unroll
        for (int j = 0; j < 4; j++)
            bfr[j] = *(const s16x8*)&Bs[wc * 64 + j * 16 + lo][hi * 8];
#pragma unroll
        for (int i = 0; i < 4; i++)
#pragma unroll
            for (int j = 0; j < 4; j++)
                acc[i][j] = __builtin_amdgcn_mfma_f32_16x16x32_bf16(
                    af[i], bfr[j], acc[i][j], 0, 0, 0);
        __syncthreads();
    }
#pragma unroll
    for (int i = 0; i < 4; i++)
#pragma unroll
        for (int j = 0; j < 4; j++)
#pragma unroll
            for (int r = 0; r < 4; r++) {
                int row = m0 + wr * 64 + i * 16 + hi * 4 + r;
                int col = n0 + wc * 64 + j * 16 + lo;
                C[(size_t)row * N + col] = acc[i][j][r];
            }
}

// ------- RoPE in-place on Q [2048][2048] bf16, fold SCALE*LOG2E -------
__global__ __launch_bounds__(256) void rope_q(
    unsigned int* __restrict__ Q, const float* __restrict__ cosT,
    const float* __restrict__ sinT) {
    int idx = blockIdx.x * 256 + threadIdx.x;  // L * 1024 pairs
    int l = idx >> 10, p = idx & 1023, i = p & 31;
    unsigned int v = Q[(size_t)l * 1024 + p];
    float x = b2f((unsigned short)(v & 0xffff));
    float y = b2f((unsigned short)(v >> 16));
    float c = cosT[l * 32 + i], s = sinT[l * 32 + i];
    float xr = (c * x - s * y) * QSC, yr = (s * x + c * y) * QSC;
    Q[(size_t)l * 1024 + p] = (unsigned int)f2b(xr) | ((unsigned int)f2b(yr) << 16);
}

// ---- RoPE in-place on K [2048][512] bf16 + write repeated f32 out ----
__global__ __launch_bounds__(256) void rope_k_out(
    unsigned int* __restrict__ K, const float* __restrict__ cosT,
    const float* __restrict__ sinT, float* __restrict__ outK) {
    int idx = blockIdx.x * 256 + threadIdx.x;  // L * 256 pairs
    int l = idx >> 8, p = idx & 255, kvh = p >> 5, i = p & 31;
    unsigned int v = K[(size_t)l * 256 + p];
    float x = b2f((unsigned short)(v & 0xffff));
    float y = b2f((unsigned short)(v >> 16));
    float c = cosT[l * 32 + i], s = sinT[l * 32 + i];
    float xr = c * x - s * y, yr = s * x + c * y;
    K[(size_t)l * 256 + p] = (unsigned int)f2b(xr) | ((unsigned int)f2b(yr) << 16);
#pragma unroll
    for (int rep = 0; rep < 4; rep++) {
        int h = kvh * 4 + rep;
        size_t o = ((size_t)h * 2048 + l) * 64 + 2 * i;
        outK[o] = xr;
        outK[o + 1] = yr;
    }
}

// ---------------- V repeated f32 out ----------------
__global__ __launch_bounds__(256) void v_out(
    const unsigned short* __restrict__ V, float* __restrict__ outV) {
    int idx = blockIdx.x * 256 + threadIdx.x;  // L * 64 chunks of 8
    int l = idx >> 6, c8 = idx & 63;
    int kvh = c8 >> 3, d0 = (c8 & 7) * 8;
    s16x8 v = *(const s16x8*)(V + (size_t)l * 512 + c8 * 8);
    float f[8];
#pragma unroll
    for (int j = 0; j < 8; j++) f[j] = b2f((unsigned short)v[j]);
#pragma unroll
    for (int rep = 0; rep < 4; rep++) {
        int h = kvh * 4 + rep;
        float* dst = outV + ((size_t)h * 2048 + l) * 64 + d0;
        *(f32x4*)dst = *(f32x4*)&f[0];
        *(f32x4*)(dst + 4) = *(f32x4*)&f[4];
    }
}

// ====================== flash attention (causal) ======================
// Swapped QK^T: S^T = mfma(A=K, B=Q). Lane (lo,hi): S^T col q=lo,
// rows k = tt*16 + hi*4 + r. In-register softmax (2 shfl per reduce),
// cvt_pk + shfl repack of P into A-fragment. No LDS, no barriers.
// Q pre-scaled by SCALE*LOG2E. Vt is V^T: [kvh*64+d][2048 k].

__device__ __forceinline__ void softmax_update(
    f32x4 s[4], float& m, float& l, f32x4 O[4], unsigned int pk[4][2],
    int hi) {
    float mx = s[0][0];
#pragma unroll
    for (int tt = 0; tt < 4; tt++)
#pragma unroll
        for (int r = 0; r < 4; r++) mx = fmaxf(mx, s[tt][r]);
    mx = fmaxf(mx, __shfl_xor(mx, 16));
    mx = fmaxf(mx, __shfl_xor(mx, 32));
    float mn = fmaxf(m, mx);
    float al = __builtin_amdgcn_exp2f(m - mn);
    m = mn;
    float rs = 0.f;
#pragma unroll
    for (int tt = 0; tt < 4; tt++) {
#pragma unroll
        for (int r = 0; r < 4; r++) {
            float p = __builtin_amdgcn_exp2f(s[tt][r] - mn);
            s[tt][r] = p;
            rs += p;
        }
        unsigned int p0, p1;
        asm("v_cvt_pk_bf16_f32 %0, %1, %2" : "=v"(p0) : "v"(s[tt][0]), "v"(s[tt][1]));
        asm("v_cvt_pk_bf16_f32 %0, %1, %2" : "=v"(p1) : "v"(s[tt][2]), "v"(s[tt][3]));
        pk[tt][0] = p0; pk[tt][1] = p1;
    }
    rs += __shfl_xor(rs, 16);
    rs += __shfl_xor(rs, 32);
    l = l * al + rs;
    float alr[4];
#pragma unroll
    for (int r = 0; r < 4; r++) alr[r] = __shfl(al, hi * 4 + r);
#pragma unroll
    for (int dt = 0; dt < 4; dt++)
#pragma unroll
        for (int r = 0; r < 4; r++) O[dt][r] *= alr[r];
}

__device__ __forceinline__ s16x8 repack_p(
    const unsigned int pk[4][2], int c, int src1, bool selB) {
    int src2 = src1 + 16;
    unsigned int tA0 = pk[2 * c][0], tA1 = pk[2 * c][1];
    unsigned int tB0 = pk[2 * c + 1][0], tB1 = pk[2 * c + 1][1];
    unsigned int a0 = __shfl((int)tA0, src1), a1 = __shfl((int)tA1, src1);
    unsigned int a2 = __shfl((int)tA0, src2), a3 = __shfl((int)tA1, src2);
    unsigned int b0 = __shfl((int)tB0, src1), b1 = __shfl((int)tB1, src1);
    unsigned int b2 = __shfl((int)tB0, src2), b3 = __shfl((int)tB1, src2);
    union { s16x8 v; unsigned int u[4]; } x;
    x.u[0] = selB ? b0 : a0;
    x.u[1] = selB ? b1 : a1;
    x.u[2] = selB ? b2 : a2;
    x.u[3] = selB ? b3 : a3;
    return x.v;
}

__global__ __launch_bounds__(256) void attn(
    const unsigned short* __restrict__ Q, const unsigned short* __restrict__ Kr,
    const unsigned short* __restrict__ Vt, unsigned short* __restrict__ Oa) {
    int h = blockIdx.x;
    int kvh = h >> 2;
    int t = threadIdx.x, wave = t >> 6, lane = t & 63, lo = lane & 15, hi = lane >> 4;
    int qw = blockIdx.y * 128 + wave * 32;

    // Q B-fragments (q=lo within group), both 32-d halves
    s16x8 qf[2][2];
#pragma unroll
    for (int g = 0; g < 2; g++)
#pragma unroll
        for (int hf = 0; hf < 2; hf++)
            qf[g][hf] = *(const s16x8*)(Q + (size_t)(qw + g * 16 + lo) * 2048 +
                                        h * 64 + hf * 32 + hi * 8);

    f32x4 O0[4] = {}, O1[4] = {};
    float m0 = -1e30f, m1 = -1e30f, l0 = 0.f, l1 = 0.f;

    const unsigned short* kp = Kr + (size_t)lo * 512 + kvh * 64 + hi * 8;
    const unsigned short* vp = Vt + (size_t)(kvh * 64 + lo) * 2048 + hi * 8;

    int src1 = lo + ((hi & 1) << 5);
    bool selB = hi >= 2;
    int kb_last = (qw + 31) >> 6;

    for (int kb = 0; kb <= kb_last; ++kb) {
        // K A-fragments: K[kb*64 + tt*16 + lo][d]
        s16x8 kf[4][2];
#pragma unroll
        for (int tt = 0; tt < 4; tt++)
#pragma unroll
            for (int hf = 0; hf < 2; hf++)
                kf[tt][hf] = *(const s16x8*)(kp + (size_t)(kb * 64 + tt * 16) * 512 +
                                             hf * 32);
        // V B-fragments: Vt[kvh*64 + dt*16 + lo][kb*64 + c*32 + hi*8]
        s16x8 vf[2][4];
#pragma unroll
        for (int c = 0; c < 2; c++)
#pragma unroll
            for (int dt = 0; dt < 4; dt++)
                vf[c][dt] = *(const s16x8*)(vp + (size_t)(dt * 16) * 2048 +
                                            kb * 64 + c * 32);

        f32x4 s0[4], s1[4];
#pragma unroll
        for (int tt = 0; tt < 4; tt++) {
            f32x4 z0 = {}, z1 = {};
            z0 = __builtin_amdgcn_mfma_f32_16x16x32_bf16(kf[tt][0], qf[0][0], z0, 0, 0, 0);
            z0 = __builtin_amdgcn_mfma_f32_16x16x32_bf16(kf[tt][1], qf[0][1], z0, 0, 0, 0);
            z1 = __builtin_amdgcn_mfma_f32_16x16x32_bf16(kf[tt][0], qf[1][0], z1, 0, 0, 0);
            z1 = __builtin_amdgcn_mfma_f32_16x16x32_bf16(kf[tt][1], qf[1][1], z1, 0, 0, 0);
            s0[tt] = z0; s1[tt] = z1;
        }

        if (kb == kb_last) {  // causal mask, wave-uniform branch
            int q0rel = qw + lo - kb * 64;
            int q1rel = q0rel + 16;
#pragma unroll
            for (int tt = 0; tt < 4; tt++)
#pragma unroll
                for (int r = 0; r < 4; r++) {
                    int kg = tt * 16 + hi * 4 + r;
                    if (kg > q0rel) s0[tt][r] = -1e30f;
                    if (kg > q1rel) s1[tt][r] = -1e30f;
                }
        }

        unsigned int pk0[4][2], pk1[4][2];
        softmax_update(s0, m0, l0, O0, pk0, hi);
        softmax_update(s1, m1, l1, O1, pk1, hi);

#pragma unroll
        for (int c = 0; c < 2; c++) {
            s16x8 pa0 = repack_p(pk0, c, src1, selB);
            s16x8 pa1 = repack_p(pk1, c, src1, selB);
#pragma unroll
            for (int dt = 0; dt < 4; dt++) {
                O0[dt] = __builtin_amdgcn_mfma_f32_16x16x32_bf16(pa0, vf[c][dt], O0[dt], 0, 0, 0);
                O1[dt] = __builtin_amdgcn_mfma_f32_16x16x32_bf16(pa1, vf[c][dt], O1[dt], 0, 0, 0);
            }
        }
    }

#pragma unroll
    for (int g = 0; g < 2; g++) {
        float lg = g ? l1 : l0;
        f32x4* O = g ? O1 : O0;
        float inv[4];
#pragma unroll
        for (int r = 0; r < 4; r++) inv[r] = 1.0f / __shfl(lg, hi * 4 + r);
        int qrow = qw + g * 16 + hi * 4;
#pragma unroll
        for (int dt = 0; dt < 4; dt++)
#pragma unroll
            for (int r = 0; r < 4; r++)
                Oa[(size_t)(qrow + r) * 2048 + h * 64 + dt * 16 + lo] =
                    f2b(O[dt][r] * inv[r]);
    }
}

extern "C" void kernel_launch(void* const* d_in, const int* in_sizes, int n_in,
                              void* d_out, int out_size, void* d_ws, size_t ws_size,
                              hipStream_t stream) {
    const float* x  = (const float*)d_in[0];
    const float* R  = (const float*)d_in[1];
    // d_in[2] = mask: unused (causal mask applied analytically)
    const float* wq = (const float*)d_in[3];
    const float* wk = (const float*)d_in[4];
    const float* wv = (const float*)d_in[5];
    const float* wo = (const float*)d_in[6];

    float* out0 = (float*)d_out;
    float* outK = out0 + (size_t)2048 * 2048;
    float* outV = outK + (size_t)32 * 2048 * 64;

    char* ws = (char*)d_ws;
    unsigned short* BTall = (unsigned short*)(ws);               // 12.0 MB [3072][2048]
    unsigned short* woT = (unsigned short*)(ws + 12582912);      // 8 MB
    unsigned short* Qb  = (unsigned short*)(ws + 20971520);      // 8 MB
    unsigned short* Kb  = (unsigned short*)(ws + 29360128);      // 2 MB
    unsigned short* Vb  = (unsigned short*)(ws + 31457280);      // 2 MB
    unsigned short* VtT = (unsigned short*)(ws + 33554432);      // 2 MB [512][2048]
    unsigned short* Ob  = (unsigned short*)(ws + 35651584);      // 8 MB
    float* cosT = (float*)(ws + 44040192);                       // 256 KB
    float* sinT = (float*)(ws + 44302336);                       // 256 KB
    unsigned short* xb  = (unsigned short*)(ws + 44564480);      // 8 MB

    cvt_f32_bf16<<<2048, 256, 0, stream>>>(x, xb);
    transpose_f32_bf16<<<dim3(32, 32), 256, 0, stream>>>(wq, BTall, 2048, 2048);
    transpose_f32_bf16<<<dim3(8, 32), 256, 0, stream>>>(wk, BTall + (size_t)2048 * 2048, 2048, 512);
    transpose_f32_bf16<<<dim3(8, 32), 256, 0, stream>>>(wv, BTall + (size_t)2560 * 2048, 2048, 512);
    transpose_f32_bf16<<<dim3(32, 32), 256, 0, stream>>>(wo, woT, 2048, 2048);
    rope_tables<<<256, 256, 0, stream>>>(R, cosT, sinT);

    gemm_qkv<<<dim3(24, 16), 256, 0, stream>>>(xb, BTall, Qb, Kb, Vb);

    rope_q<<<8192, 256, 0, stream>>>((unsigned int*)Qb, cosT, sinT);
    rope_k_out<<<2048, 256, 0, stream>>>((unsigned int*)Kb, cosT, sinT, outK);
    v_out<<<512, 256, 0, stream>>>(Vb, outV);
    transpose_bf16<<<dim3(8, 32), 256, 0, stream>>>(Vb, VtT, 2048, 512);

    attn<<<dim3(32, 16), 256, 0, stream>>>(Qb, Kb, VtT, Ob);

    gemm_out<<<dim3(16, 16), 256, 0, stream>>>(Ob, woT, out0, 2048, 2048, 2048);
}